// Round 1
// baseline (2108.747 us; speedup 1.0000x reference)
//
#include <hip/hip_runtime.h>

// ---------------------------------------------------------------------------
// GINE model forward on MI355X. f32 throughout.
// N=100000 nodes, E=1600000 edges, G=128 graphs, DIM=64, 4 layers.
// ---------------------------------------------------------------------------

#define DIM 64
#define NGRAPH 128
#define SCAN_B 1024

// ---------------- node encoder: h = x @ W(32x64) + b ----------------------
__global__ __launch_bounds__(256) void node_enc_kernel(
    const float* __restrict__ x, const float* __restrict__ W,
    const float* __restrict__ b, float* __restrict__ h, int N)
{
  int lane = threadIdx.x & 63;
  int wave = (blockIdx.x * blockDim.x + threadIdx.x) >> 6;
  int nw = (gridDim.x * blockDim.x) >> 6;
  float wcol[32];
#pragma unroll
  for (int k = 0; k < 32; ++k) wcol[k] = W[k * 64 + lane];
  float bb = b[lane];
  for (int n = wave; n < N; n += nw) {
    const float4* xr = (const float4*)(x + (size_t)n * 32);
    float acc = bb;
#pragma unroll
    for (int c = 0; c < 8; ++c) {
      float4 v = xr[c];
      acc = fmaf(v.x, wcol[4 * c + 0], acc);
      acc = fmaf(v.y, wcol[4 * c + 1], acc);
      acc = fmaf(v.z, wcol[4 * c + 2], acc);
      acc = fmaf(v.w, wcol[4 * c + 3], acc);
    }
    h[(size_t)n * 64 + lane] = acc;
  }
}

// ---------------- CSR build ------------------------------------------------
__global__ __launch_bounds__(256) void count_kernel(
    const int* __restrict__ dst, int* __restrict__ deg, int E)
{
  int e = blockIdx.x * blockDim.x + threadIdx.x;
  if (e < E) atomicAdd(&deg[dst[e]], 1);
}

__global__ __launch_bounds__(SCAN_B) void scan1_kernel(
    const int* __restrict__ deg, int* __restrict__ rowp,
    int* __restrict__ bsum, int N)
{
  __shared__ int s[SCAN_B];
  int tid = threadIdx.x;
  int i = blockIdx.x * SCAN_B + tid;
  int v = (i < N) ? deg[i] : 0;
  s[tid] = v;
  __syncthreads();
  for (int off = 1; off < SCAN_B; off <<= 1) {
    int t = (tid >= off) ? s[tid - off] : 0;
    __syncthreads();
    s[tid] += t;
    __syncthreads();
  }
  if (i < N) rowp[i] = s[tid] - v;          // exclusive
  if (tid == SCAN_B - 1) bsum[blockIdx.x] = s[tid];
}

__global__ __launch_bounds__(128) void scan2_kernel(int* __restrict__ bsum, int NB)
{
  __shared__ int s[128];
  int tid = threadIdx.x;
  int v = (tid < NB) ? bsum[tid] : 0;
  s[tid] = v;
  __syncthreads();
  for (int off = 1; off < 128; off <<= 1) {
    int t = (tid >= off) ? s[tid - off] : 0;
    __syncthreads();
    s[tid] += t;
    __syncthreads();
  }
  if (tid < NB) bsum[tid] = s[tid] - v;     // exclusive block offsets
}

__global__ __launch_bounds__(SCAN_B) void scan3_kernel(
    int* __restrict__ rowp, const int* __restrict__ bsum, int N, int E)
{
  int i = blockIdx.x * SCAN_B + threadIdx.x;
  if (i < N) rowp[i] += bsum[blockIdx.x];
  if (i == 0) rowp[N] = E;
}

__global__ __launch_bounds__(256) void scatter_kernel(
    const int* __restrict__ dst, const int* __restrict__ rowp,
    int* __restrict__ fill, int* __restrict__ eids, int E)
{
  int e = blockIdx.x * blockDim.x + threadIdx.x;
  if (e < E) {
    int d = dst[e];
    int pos = rowp[d] + atomicAdd(&fill[d], 1);
    eids[pos] = e;
  }
}

// ---------------- gather: z[i] = h[i] + sum_{e: dst=i} relu(h[src]+enc(attr))
__global__ __launch_bounds__(256) void gather_kernel(
    const float* __restrict__ h, const float* __restrict__ edge_attr,
    const int* __restrict__ src, const int* __restrict__ eids,
    const int* __restrict__ rowp, const float* __restrict__ eW,
    const float* __restrict__ eb_, float* __restrict__ z, int N)
{
  int lane = threadIdx.x & 63;
  int node = (blockIdx.x * blockDim.x + threadIdx.x) >> 6;
  if (node >= N) return;
  float wcol[16];
#pragma unroll
  for (int k = 0; k < 16; ++k) wcol[k] = eW[k * 64 + lane];
  float eb = eb_[lane];
  float acc = 0.f;
  int j0 = rowp[node], j1 = rowp[node + 1];
  for (int j = j0; j < j1; ++j) {
    int eid = eids[j];
    int s = src[eid];
    const float4* ar = (const float4*)(edge_attr + (size_t)eid * 16);
    float4 a0 = ar[0], a1 = ar[1], a2 = ar[2], a3 = ar[3];
    float m = eb;
    m = fmaf(a0.x, wcol[0], m);  m = fmaf(a0.y, wcol[1], m);
    m = fmaf(a0.z, wcol[2], m);  m = fmaf(a0.w, wcol[3], m);
    m = fmaf(a1.x, wcol[4], m);  m = fmaf(a1.y, wcol[5], m);
    m = fmaf(a1.z, wcol[6], m);  m = fmaf(a1.w, wcol[7], m);
    m = fmaf(a2.x, wcol[8], m);  m = fmaf(a2.y, wcol[9], m);
    m = fmaf(a2.z, wcol[10], m); m = fmaf(a2.w, wcol[11], m);
    m = fmaf(a3.x, wcol[12], m); m = fmaf(a3.y, wcol[13], m);
    m = fmaf(a3.z, wcol[14], m); m = fmaf(a3.w, wcol[15], m);
    float hv = h[(size_t)s * 64 + lane];
    acc += fmaxf(hv + m, 0.f);
  }
  z[(size_t)node * 64 + lane] = h[(size_t)node * 64 + lane] + acc;
}

// ---------------- dense 64x64 matmul over N rows (thread-per-row) ----------
__global__ __launch_bounds__(256) void mlp_kernel(
    const float* __restrict__ in, float* __restrict__ out,
    const float* __restrict__ W, const float* __restrict__ b,
    int N, int do_relu)
{
  int row = blockIdx.x * 256 + threadIdx.x;
  if (row >= N) return;
  float y[64];
#pragma unroll
  for (int d = 0; d < 64; ++d) y[d] = b[d];
  const float4* ir = (const float4*)(in + (size_t)row * 64);
  for (int kk = 0; kk < 16; ++kk) {
    float4 v = ir[kk];
    const float* w = W + kk * 256;   // 4 consecutive weight rows
#pragma unroll
    for (int d = 0; d < 64; ++d) {
      float t = fmaf(v.x, w[d],
                fmaf(v.y, w[64 + d],
                fmaf(v.z, w[128 + d], v.w * w[192 + d])));
      y[d] += t;
    }
  }
  if (do_relu) {
#pragma unroll
    for (int d = 0; d < 64; ++d) y[d] = fmaxf(y[d], 0.f);
  }
  float4* orow = (float4*)(out + (size_t)row * 64);
#pragma unroll
  for (int c = 0; c < 16; ++c) {
    float4 v;
    v.x = y[4 * c]; v.y = y[4 * c + 1]; v.z = y[4 * c + 2]; v.w = y[4 * c + 3];
    orow[c] = v;
  }
}

// ---------------- BN stats / finalize / normalize --------------------------
__global__ __launch_bounds__(256) void bnstats_kernel(
    const float* __restrict__ z, float* __restrict__ stat, int N)
{
  int lane = threadIdx.x & 63;
  int wave = (blockIdx.x * blockDim.x + threadIdx.x) >> 6;
  int nw = (gridDim.x * blockDim.x) >> 6;
  float s1 = 0.f, s2 = 0.f;
  for (int r = wave; r < N; r += nw) {
    float v = z[(size_t)r * 64 + lane];
    s1 += v;
    s2 = fmaf(v, v, s2);
  }
  atomicAdd(&stat[lane], s1);
  atomicAdd(&stat[64 + lane], s2);
}

__global__ __launch_bounds__(64) void bnfinal_kernel(
    const float* __restrict__ stat, const float* __restrict__ gamma,
    const float* __restrict__ beta, float* __restrict__ scsh, float invN)
{
  int d = threadIdx.x;
  float mu = stat[d] * invN;
  float var = stat[64 + d] * invN - mu * mu;
  var = fmaxf(var, 0.f);
  float sc = gamma[d] * rsqrtf(var + 1e-5f);
  scsh[d] = sc;
  scsh[64 + d] = beta[d] - mu * sc;
}

__global__ __launch_bounds__(256) void bnnorm_kernel(
    const float4* __restrict__ z4, const float* __restrict__ scsh,
    float4* __restrict__ h4, int n4)
{
  int i = blockIdx.x * blockDim.x + threadIdx.x;
  if (i >= n4) return;
  int d0 = (i & 15) * 4;
  float4 v = z4[i];
  float4 r;
  r.x = fmaxf(fmaf(v.x, scsh[d0 + 0], scsh[64 + d0 + 0]), 0.f);
  r.y = fmaxf(fmaf(v.y, scsh[d0 + 1], scsh[64 + d0 + 1]), 0.f);
  r.z = fmaxf(fmaf(v.z, scsh[d0 + 2], scsh[64 + d0 + 2]), 0.f);
  r.w = fmaxf(fmaf(v.w, scsh[d0 + 3], scsh[64 + d0 + 3]), 0.f);
  h4[i] = r;
}

// ---------------- pooling over sorted batch --------------------------------
__global__ __launch_bounds__(256) void pool_kernel(
    const float* __restrict__ h, const int* __restrict__ batch,
    float* __restrict__ sums, float* __restrict__ cnts, int N)
{
  int lane = threadIdx.x & 63;
  int wave = (blockIdx.x * blockDim.x + threadIdx.x) >> 6;
  int r0 = wave * 64;
  if (r0 >= N) return;
  int r1 = min(r0 + 64, N);
  int cur = batch[r0];
  float acc = 0.f;
  int cnt = 0;
  for (int r = r0; r < r1; ++r) {
    int bg = batch[r];
    if (bg != cur) {
      atomicAdd(&sums[(size_t)cur * 64 + lane], acc);
      if (lane == 0) atomicAdd(&cnts[cur], (float)cnt);
      acc = 0.f; cnt = 0; cur = bg;
    }
    acc += h[(size_t)r * 64 + lane];
    cnt++;
  }
  atomicAdd(&sums[(size_t)cur * 64 + lane], acc);
  if (lane == 0) atomicAdd(&cnts[cur], (float)cnt);
}

// ---------------- head: per-graph MLP --------------------------------------
__global__ __launch_bounds__(256) void head_kernel(
    const float* __restrict__ sums, const float* __restrict__ cnts,
    const float* __restrict__ W1, const float* __restrict__ b1,
    const float* __restrict__ W2, const float* __restrict__ b2,
    const float* __restrict__ W3, const float* __restrict__ b3,
    float* __restrict__ out)
{
  __shared__ float gf[128];
  __shared__ float h1s[256];
  __shared__ float h2s[128];
  int g = blockIdx.x, t = threadIdx.x;
  if (t < 64) {
    float sv = sums[(size_t)g * 64 + t];
    gf[t] = sv;
    gf[64 + t] = sv / fmaxf(cnts[g], 1.f);
  }
  __syncthreads();
  float a = b1[t];
  for (int k = 0; k < 128; ++k) a = fmaf(gf[k], W1[k * 256 + t], a);
  h1s[t] = fmaxf(a, 0.f);
  __syncthreads();
  if (t < 128) {
    float a2 = b2[t];
    for (int k = 0; k < 256; ++k) a2 = fmaf(h1s[k], W2[k * 128 + t], a2);
    h2s[t] = fmaxf(a2, 0.f);
  }
  __syncthreads();
  if (t == 0) {
    float s = b3[0];
    for (int k = 0; k < 128; ++k) s = fmaf(h2s[k], W3[k], s);
    out[g] = s;
  }
}

// ---------------------------------------------------------------------------
extern "C" void kernel_launch(void* const* d_in, const int* in_sizes, int n_in,
                              void* d_out, int out_size, void* d_ws, size_t ws_size,
                              hipStream_t stream)
{
  const float* x         = (const float*)d_in[0];
  const float* edge_attr = (const float*)d_in[1];
  const int*   ei        = (const int*)  d_in[2];
  const int*   batch     = (const int*)  d_in[3];
  const float* node_W    = (const float*)d_in[4];
  const float* node_b    = (const float*)d_in[5];
  const float* edge_W    = (const float*)d_in[6];
  const float* edge_b    = (const float*)d_in[7];
  const float* mlp1_W    = (const float*)d_in[8];
  const float* mlp1_b    = (const float*)d_in[9];
  const float* mlp2_W    = (const float*)d_in[10];
  const float* mlp2_b    = (const float*)d_in[11];
  const float* bn_gamma  = (const float*)d_in[12];
  const float* bn_beta   = (const float*)d_in[13];
  const float* head1_W   = (const float*)d_in[14];
  const float* head1_b   = (const float*)d_in[15];
  const float* head2_W   = (const float*)d_in[16];
  const float* head2_b   = (const float*)d_in[17];
  const float* head3_W   = (const float*)d_in[18];
  const float* head3_b   = (const float*)d_in[19];
  float* out = (float*)d_out;

  const int N = in_sizes[0] / 32;       // 100000
  const int E = in_sizes[2] / 2;        // 1600000
  const int* srcp = ei;
  const int* dstp = ei + E;

  // ---- workspace layout ----
  char* ws = (char*)d_ws;
  size_t off = 0;
  auto alloc = [&](size_t bytes) -> void* {
    void* p = ws + off;
    off += (bytes + 255) & ~(size_t)255;
    return p;
  };
  float* h    = (float*)alloc((size_t)N * 64 * 4);
  float* z    = (float*)alloc((size_t)N * 64 * 4);
  float* yb   = (float*)alloc((size_t)N * 64 * 4);
  int*   deg  = (int*)  alloc((size_t)N * 4);
  int*   rowp = (int*)  alloc((size_t)(N + 1) * 4);
  int*   bsum = (int*)  alloc(512);
  int*   fill = (int*)  alloc((size_t)N * 4);
  int*   eids = (int*)  alloc((size_t)E * 4);
  float* stat = (float*)alloc(512);
  float* scsh = (float*)alloc(512);
  float* sums = (float*)alloc((size_t)NGRAPH * 64 * 4);
  float* cnts = (float*)alloc((size_t)NGRAPH * 4);
  (void)ws_size; (void)n_in; (void)out_size;

  const int NB = (N + SCAN_B - 1) / SCAN_B;   // 98

  // ---- encoders + CSR build ----
  hipMemsetAsync(deg, 0, (size_t)N * 4, stream);
  hipMemsetAsync(fill, 0, (size_t)N * 4, stream);

  node_enc_kernel<<<2048, 256, 0, stream>>>(x, node_W, node_b, h, N);
  count_kernel<<<(E + 255) / 256, 256, 0, stream>>>(dstp, deg, E);
  scan1_kernel<<<NB, SCAN_B, 0, stream>>>(deg, rowp, bsum, N);
  scan2_kernel<<<1, 128, 0, stream>>>(bsum, NB);
  scan3_kernel<<<NB, SCAN_B, 0, stream>>>(rowp, bsum, N, E);
  scatter_kernel<<<(E + 255) / 256, 256, 0, stream>>>(dstp, rowp, fill, eids, E);

  // ---- 4 GINE layers ----
  const int gatherBlocks = (N + 3) / 4;          // 1 wave per node
  const int mlpBlocks    = (N + 255) / 256;
  const int n4           = N * 16;
  for (int l = 0; l < 4; ++l) {
    gather_kernel<<<gatherBlocks, 256, 0, stream>>>(
        h, edge_attr, srcp, eids, rowp, edge_W, edge_b, z, N);
    mlp_kernel<<<mlpBlocks, 256, 0, stream>>>(
        z, yb, mlp1_W + (size_t)l * 4096, mlp1_b + (size_t)l * 64, N, 1);
    mlp_kernel<<<mlpBlocks, 256, 0, stream>>>(
        yb, z, mlp2_W + (size_t)l * 4096, mlp2_b + (size_t)l * 64, N, 0);
    hipMemsetAsync(stat, 0, 512, stream);
    bnstats_kernel<<<1024, 256, 0, stream>>>(z, stat, N);
    bnfinal_kernel<<<1, 64, 0, stream>>>(
        stat, bn_gamma + (size_t)l * 64, bn_beta + (size_t)l * 64, scsh, 1.0f / (float)N);
    bnnorm_kernel<<<(n4 + 255) / 256, 256, 0, stream>>>(
        (const float4*)z, scsh, (float4*)h, n4);
  }

  // ---- pooling + head ----
  hipMemsetAsync(sums, 0, (size_t)NGRAPH * 64 * 4, stream);
  hipMemsetAsync(cnts, 0, (size_t)NGRAPH * 4, stream);
  const int poolWaves = (N + 63) / 64;
  pool_kernel<<<(poolWaves + 3) / 4, 256, 0, stream>>>(h, batch, sums, cnts, N);
  head_kernel<<<NGRAPH, 256, 0, stream>>>(
      sums, cnts, head1_W, head1_b, head2_W, head2_b, head3_W, head3_b, out);
}

// Round 2
// 1588.363 us; speedup vs baseline: 1.3276x; 1.3276x over previous
//
#include <hip/hip_runtime.h>

#define SCAN_B 1024
#define NGRAPH 128

// ---------------- node encoder: h = x @ W(32x64) + b ----------------------
__global__ __launch_bounds__(256) void node_enc_kernel(
    const float* __restrict__ x, const float* __restrict__ W,
    const float* __restrict__ b, float* __restrict__ h, int N)
{
  int lane = threadIdx.x & 63;
  int wave = (blockIdx.x * blockDim.x + threadIdx.x) >> 6;
  int nw = (gridDim.x * blockDim.x) >> 6;
  float wcol[32];
#pragma unroll
  for (int k = 0; k < 32; ++k) wcol[k] = W[k * 64 + lane];
  float bb = b[lane];
  for (int n = wave; n < N; n += nw) {
    const float4* xr = (const float4*)(x + (size_t)n * 32);
    float acc = bb;
#pragma unroll
    for (int c = 0; c < 8; ++c) {
      float4 v = xr[c];
      acc = fmaf(v.x, wcol[4 * c + 0], acc);
      acc = fmaf(v.y, wcol[4 * c + 1], acc);
      acc = fmaf(v.z, wcol[4 * c + 2], acc);
      acc = fmaf(v.w, wcol[4 * c + 3], acc);
    }
    h[(size_t)n * 64 + lane] = acc;
  }
}

// ---------------- CSR build ------------------------------------------------
__global__ __launch_bounds__(256) void count_kernel(
    const int* __restrict__ dst, int* __restrict__ deg, int E)
{
  int e = blockIdx.x * blockDim.x + threadIdx.x;
  if (e < E) atomicAdd(&deg[dst[e]], 1);
}

__global__ __launch_bounds__(SCAN_B) void scan1_kernel(
    const int* __restrict__ deg, int* __restrict__ rowp,
    int* __restrict__ bsum, int N)
{
  __shared__ int s[SCAN_B];
  int tid = threadIdx.x;
  int i = blockIdx.x * SCAN_B + tid;
  int v = (i < N) ? deg[i] : 0;
  s[tid] = v;
  __syncthreads();
  for (int off = 1; off < SCAN_B; off <<= 1) {
    int t = (tid >= off) ? s[tid - off] : 0;
    __syncthreads();
    s[tid] += t;
    __syncthreads();
  }
  if (i < N) rowp[i] = s[tid] - v;          // exclusive
  if (tid == SCAN_B - 1) bsum[blockIdx.x] = s[tid];
}

__global__ __launch_bounds__(128) void scan2_kernel(int* __restrict__ bsum, int NB)
{
  __shared__ int s[128];
  int tid = threadIdx.x;
  int v = (tid < NB) ? bsum[tid] : 0;
  s[tid] = v;
  __syncthreads();
  for (int off = 1; off < 128; off <<= 1) {
    int t = (tid >= off) ? s[tid - off] : 0;
    __syncthreads();
    s[tid] += t;
    __syncthreads();
  }
  if (tid < NB) bsum[tid] = s[tid] - v;     // exclusive block offsets
}

__global__ __launch_bounds__(SCAN_B) void scan3_kernel(
    int* __restrict__ rowp, const int* __restrict__ bsum, int N, int E)
{
  int i = blockIdx.x * SCAN_B + threadIdx.x;
  if (i < N) rowp[i] += bsum[blockIdx.x];
  if (i == 0) rowp[N] = E;
}

__global__ __launch_bounds__(256) void scatter_kernel(
    const int* __restrict__ dst, const int* __restrict__ rowp,
    int* __restrict__ fill, int* __restrict__ eids, int E)
{
  int e = blockIdx.x * blockDim.x + threadIdx.x;
  if (e < E) {
    int d = dst[e];
    int pos = rowp[d] + atomicAdd(&fill[d], 1);
    eids[pos] = e;
  }
}

// ---------------- permute edge data into CSR order -------------------------
__global__ __launch_bounds__(256) void permute_kernel(
    const int* __restrict__ eids, const int* __restrict__ src,
    const float4* __restrict__ attr4, int* __restrict__ src_s,
    float4* __restrict__ attr_s4, int E)
{
  int j = blockIdx.x * 256 + threadIdx.x;
  if (j >= E) return;
  int eid = eids[j];
  src_s[j] = src[eid];
  float4 a0 = attr4[(size_t)eid * 4 + 0];
  float4 a1 = attr4[(size_t)eid * 4 + 1];
  float4 a2 = attr4[(size_t)eid * 4 + 2];
  float4 a3 = attr4[(size_t)eid * 4 + 3];
  attr_s4[(size_t)j * 4 + 0] = a0;
  attr_s4[(size_t)j * 4 + 1] = a1;
  attr_s4[(size_t)j * 4 + 2] = a2;
  attr_s4[(size_t)j * 4 + 3] = a3;
}

// ---------------- gather (fused BN-normalize of input z) -------------------
// out[i] = hnorm(i) + sum_{e: dst=i} relu(hnorm(src_e) + enc(attr_e))
// hnorm(v) = use_bn ? relu(v*sc+sh) : v
template<bool SORTED>
__global__ __launch_bounds__(256) void gather_kernel(
    const float* __restrict__ z, const float* __restrict__ scsh,
    const float* __restrict__ attr,   // SORTED ? attr_s : edge_attr
    const int*   __restrict__ srcv,   // SORTED ? src_s : src
    const int*   __restrict__ eids,   // used when !SORTED
    const int*   __restrict__ rowp,
    const float* __restrict__ eW, const float* __restrict__ eb_,
    float* __restrict__ g, int N, int use_bn)
{
  int lane = threadIdx.x & 63;
  int node = (blockIdx.x * blockDim.x + threadIdx.x) >> 6;
  if (node >= N) return;
  float wcol[16];
#pragma unroll
  for (int k = 0; k < 16; ++k) wcol[k] = eW[k * 64 + lane];
  const float eb = eb_[lane];
  float sc = 1.f, sh = 0.f;
  if (use_bn) { sc = scsh[lane]; sh = scsh[64 + lane]; }

  auto edot = [&](int idx) -> float {
    const float4* ar = (const float4*)(attr + (size_t)idx * 16);
    float4 a0 = ar[0], a1 = ar[1], a2 = ar[2], a3 = ar[3];
    float m = eb;
    m = fmaf(a0.x, wcol[0], m);  m = fmaf(a0.y, wcol[1], m);
    m = fmaf(a0.z, wcol[2], m);  m = fmaf(a0.w, wcol[3], m);
    m = fmaf(a1.x, wcol[4], m);  m = fmaf(a1.y, wcol[5], m);
    m = fmaf(a1.z, wcol[6], m);  m = fmaf(a1.w, wcol[7], m);
    m = fmaf(a2.x, wcol[8], m);  m = fmaf(a2.y, wcol[9], m);
    m = fmaf(a2.z, wcol[10], m); m = fmaf(a2.w, wcol[11], m);
    m = fmaf(a3.x, wcol[12], m); m = fmaf(a3.y, wcol[13], m);
    m = fmaf(a3.z, wcol[14], m); m = fmaf(a3.w, wcol[15], m);
    return m;
  };
  auto hval = [&](float zz) -> float {
    return use_bn ? fmaxf(fmaf(zz, sc, sh), 0.f) : zz;
  };

  const int j0 = rowp[node], j1 = rowp[node + 1];
  float zv = z[(size_t)node * 64 + lane];
  float acc = hval(zv);

  for (int base = j0; base < j1; base += 64) {
    int nb = j1 - base; if (nb > 64) nb = 64;
    int iv = 0;
    if (base + lane < j1) iv = SORTED ? srcv[base + lane] : eids[base + lane];
    int t = 0;
    for (; t + 4 <= nb; t += 4) {
      int i0 = __shfl(iv, t, 64),     i1 = __shfl(iv, t + 1, 64);
      int i2 = __shfl(iv, t + 2, 64), i3 = __shfl(iv, t + 3, 64);
      int s0, s1, s2, s3;
      if (SORTED) { s0 = i0; s1 = i1; s2 = i2; s3 = i3; }
      else { s0 = srcv[i0]; s1 = srcv[i1]; s2 = srcv[i2]; s3 = srcv[i3]; }
      float z0 = z[(size_t)s0 * 64 + lane];
      float z1 = z[(size_t)s1 * 64 + lane];
      float z2 = z[(size_t)s2 * 64 + lane];
      float z3 = z[(size_t)s3 * 64 + lane];
      float m0 = edot(SORTED ? (base + t)     : i0);
      float m1 = edot(SORTED ? (base + t + 1) : i1);
      float m2 = edot(SORTED ? (base + t + 2) : i2);
      float m3 = edot(SORTED ? (base + t + 3) : i3);
      acc += fmaxf(hval(z0) + m0, 0.f) + fmaxf(hval(z1) + m1, 0.f)
           + fmaxf(hval(z2) + m2, 0.f) + fmaxf(hval(z3) + m3, 0.f);
    }
    for (; t < nb; ++t) {
      int i0 = __shfl(iv, t, 64);
      int s0 = SORTED ? i0 : srcv[i0];
      float z0 = z[(size_t)s0 * 64 + lane];
      float m0 = edot(SORTED ? (base + t) : i0);
      acc += fmaxf(hval(z0) + m0, 0.f);
    }
  }
  g[(size_t)node * 64 + lane] = acc;
}

// ---------------- fused MLP (two 64x64 matmuls) + BN stats -----------------
__global__ __launch_bounds__(256, 2) void mlp_fused_kernel(
    const float* __restrict__ g, float* __restrict__ z,
    const float* __restrict__ W1, const float* __restrict__ b1,
    const float* __restrict__ W2, const float* __restrict__ b2,
    float* __restrict__ stat, int N)
{
  __shared__ float sred[2][4][64];
  int tid = threadIdx.x, lane = tid & 63, w = tid >> 6;
  int row = blockIdx.x * 256 + tid;
  bool active = row < N;
  int r = active ? row : (N - 1);

  float y1[64];
#pragma unroll
  for (int d = 0; d < 64; ++d) y1[d] = b1[d];
  const float4* gr = (const float4*)(g + (size_t)r * 64);
  for (int kk = 0; kk < 16; ++kk) {
    float4 v = gr[kk];
    const float* wp = W1 + kk * 256;
#pragma unroll
    for (int d = 0; d < 64; ++d)
      y1[d] += fmaf(v.x, wp[d], fmaf(v.y, wp[64 + d],
               fmaf(v.z, wp[128 + d], v.w * wp[192 + d])));
  }
#pragma unroll
  for (int d = 0; d < 64; ++d) y1[d] = fmaxf(y1[d], 0.f);

  float y2[64];
#pragma unroll
  for (int d = 0; d < 64; ++d) y2[d] = b2[d];
  for (int kk = 0; kk < 16; ++kk) {
    const float* wp = W2 + kk * 256;
    float vx = y1[4 * kk], vy = y1[4 * kk + 1];
    float vz = y1[4 * kk + 2], vw = y1[4 * kk + 3];
#pragma unroll
    for (int d = 0; d < 64; ++d)
      y2[d] += fmaf(vx, wp[d], fmaf(vy, wp[64 + d],
               fmaf(vz, wp[128 + d], vw * wp[192 + d])));
  }

  if (active) {
    float4* zr = (float4*)(z + (size_t)row * 64);
#pragma unroll
    for (int c = 0; c < 16; ++c)
      zr[c] = make_float4(y2[4 * c], y2[4 * c + 1], y2[4 * c + 2], y2[4 * c + 3]);
  }

  // per-channel sum / sumsq: butterfly within wave, channel d lands on lane d
  float mask = active ? 1.f : 0.f;
  float rs1 = 0.f, rs2 = 0.f;
#pragma unroll
  for (int d = 0; d < 64; ++d) {
    float a = y2[d] * mask;
    float bq = a * a;
#pragma unroll
    for (int m = 1; m < 64; m <<= 1) {
      a += __shfl_xor(a, m, 64);
      bq += __shfl_xor(bq, m, 64);
    }
    if (lane == d) { rs1 = a; rs2 = bq; }
  }
  sred[0][w][lane] = rs1;
  sred[1][w][lane] = rs2;
  __syncthreads();
  if (tid < 64) {
    atomicAdd(&stat[tid],
              sred[0][0][tid] + sred[0][1][tid] + sred[0][2][tid] + sred[0][3][tid]);
  } else if (tid < 128) {
    int c = tid - 64;
    atomicAdd(&stat[64 + c],
              sred[1][0][c] + sred[1][1][c] + sred[1][2][c] + sred[1][3][c]);
  }
}

// ---------------- BN finalize ----------------------------------------------
__global__ __launch_bounds__(64) void bnfinal_kernel(
    const float* __restrict__ stat, const float* __restrict__ gamma,
    const float* __restrict__ beta, float* __restrict__ scsh, float invN)
{
  int d = threadIdx.x;
  float mu = stat[d] * invN;
  float var = stat[64 + d] * invN - mu * mu;
  var = fmaxf(var, 0.f);
  float sc = gamma[d] * rsqrtf(var + 1e-5f);
  scsh[d] = sc;
  scsh[64 + d] = beta[d] - mu * sc;
}

// ---------------- pooling (fused BN-normalize + relu) ----------------------
__global__ __launch_bounds__(256) void pool_kernel(
    const float* __restrict__ z, const float* __restrict__ scsh,
    const int* __restrict__ batch,
    float* __restrict__ sums, float* __restrict__ cnts, int N)
{
  int lane = threadIdx.x & 63;
  int wave = (blockIdx.x * blockDim.x + threadIdx.x) >> 6;
  int r0 = wave * 64;
  if (r0 >= N) return;
  float sc = scsh[lane], sh = scsh[64 + lane];
  int r1 = min(r0 + 64, N);
  int cur = batch[r0];
  float acc = 0.f;
  int cnt = 0;
  for (int r = r0; r < r1; ++r) {
    int bg = batch[r];
    if (bg != cur) {
      atomicAdd(&sums[(size_t)cur * 64 + lane], acc);
      if (lane == 0) atomicAdd(&cnts[cur], (float)cnt);
      acc = 0.f; cnt = 0; cur = bg;
    }
    acc += fmaxf(fmaf(z[(size_t)r * 64 + lane], sc, sh), 0.f);
    cnt++;
  }
  atomicAdd(&sums[(size_t)cur * 64 + lane], acc);
  if (lane == 0) atomicAdd(&cnts[cur], (float)cnt);
}

// ---------------- head: per-graph MLP --------------------------------------
__global__ __launch_bounds__(256) void head_kernel(
    const float* __restrict__ sums, const float* __restrict__ cnts,
    const float* __restrict__ W1, const float* __restrict__ b1,
    const float* __restrict__ W2, const float* __restrict__ b2,
    const float* __restrict__ W3, const float* __restrict__ b3,
    float* __restrict__ out)
{
  __shared__ float gf[128];
  __shared__ float h1s[256];
  __shared__ float h2s[128];
  int g = blockIdx.x, t = threadIdx.x;
  if (t < 64) {
    float sv = sums[(size_t)g * 64 + t];
    gf[t] = sv;
    gf[64 + t] = sv / fmaxf(cnts[g], 1.f);
  }
  __syncthreads();
  float a = b1[t];
  for (int k = 0; k < 128; ++k) a = fmaf(gf[k], W1[k * 256 + t], a);
  h1s[t] = fmaxf(a, 0.f);
  __syncthreads();
  if (t < 128) {
    float a2 = b2[t];
    for (int k = 0; k < 256; ++k) a2 = fmaf(h1s[k], W2[k * 128 + t], a2);
    h2s[t] = fmaxf(a2, 0.f);
  }
  __syncthreads();
  if (t == 0) {
    float s = b3[0];
    for (int k = 0; k < 128; ++k) s = fmaf(h2s[k], W3[k], s);
    out[g] = s;
  }
}

// ---------------------------------------------------------------------------
extern "C" void kernel_launch(void* const* d_in, const int* in_sizes, int n_in,
                              void* d_out, int out_size, void* d_ws, size_t ws_size,
                              hipStream_t stream)
{
  const float* x         = (const float*)d_in[0];
  const float* edge_attr = (const float*)d_in[1];
  const int*   ei        = (const int*)  d_in[2];
  const int*   batch     = (const int*)  d_in[3];
  const float* node_W    = (const float*)d_in[4];
  const float* node_b    = (const float*)d_in[5];
  const float* edge_W    = (const float*)d_in[6];
  const float* edge_b    = (const float*)d_in[7];
  const float* mlp1_W    = (const float*)d_in[8];
  const float* mlp1_b    = (const float*)d_in[9];
  const float* mlp2_W    = (const float*)d_in[10];
  const float* mlp2_b    = (const float*)d_in[11];
  const float* bn_gamma  = (const float*)d_in[12];
  const float* bn_beta   = (const float*)d_in[13];
  const float* head1_W   = (const float*)d_in[14];
  const float* head1_b   = (const float*)d_in[15];
  const float* head2_W   = (const float*)d_in[16];
  const float* head2_b   = (const float*)d_in[17];
  const float* head3_W   = (const float*)d_in[18];
  const float* head3_b   = (const float*)d_in[19];
  float* out = (float*)d_out;
  (void)n_in; (void)out_size;

  const int N = in_sizes[0] / 32;       // 100000
  const int E = in_sizes[2] / 2;        // 1600000
  const int* srcp = ei;
  const int* dstp = ei + E;

  auto al = [](size_t b) { return (b + 255) & ~(size_t)255; };
  const size_t sz_z    = al((size_t)N * 64 * 4);
  const size_t sz_rowp = al((size_t)(N + 1) * 4);
  const size_t sz_attr = al((size_t)E * 16 * 4);
  const size_t sz_src  = al((size_t)E * 4);
  const size_t sz_eids = al((size_t)E * 4);
  const size_t sz_small = al(512) * 3 + al(NGRAPH * 64 * 4) + al(NGRAPH * 4);

  const size_t need_sorted = 2 * sz_z + sz_rowp + sz_attr + sz_src + sz_small;
  const bool sorted = ws_size >= need_sorted;

  char* p = (char*)d_ws;
  auto take = [&](size_t b) -> char* { char* q = p; p += b; return q; };

  float* zbuf = (float*)take(sz_z);
  float* gbuf = (float*)take(sz_z);
  int*   rowp = (int*)  take(sz_rowp);
  float* stat = (float*)take(al(512));
  float* scsh = (float*)take(al(512));
  int*   bsum = (int*)  take(al(512));
  float* sums = (float*)take(al(NGRAPH * 64 * 4));
  float* cnts = (float*)take(al(NGRAPH * 4));

  float* attr_s = nullptr;
  int*   src_s  = nullptr;
  int*   eids;
  int*   deg;
  int*   fill;
  if (sorted) {
    attr_s = (float*)take(sz_attr);
    src_s  = (int*)  take(sz_src);
    // scratch (only live before first gather) aliases gbuf
    deg  = (int*)gbuf;
    fill = (int*)((char*)gbuf + al((size_t)N * 4));
    eids = (int*)((char*)gbuf + 2 * al((size_t)N * 4));
  } else {
    eids = (int*)take(sz_eids);
    deg  = (int*)gbuf;
    fill = (int*)((char*)gbuf + al((size_t)N * 4));
  }

  const int NB = (N + SCAN_B - 1) / SCAN_B;

  // ---- encoders + CSR build ----
  hipMemsetAsync(deg,  0, (size_t)N * 4, stream);
  hipMemsetAsync(fill, 0, (size_t)N * 4, stream);

  node_enc_kernel<<<2048, 256, 0, stream>>>(x, node_W, node_b, zbuf, N);
  count_kernel<<<(E + 255) / 256, 256, 0, stream>>>(dstp, deg, E);
  scan1_kernel<<<NB, SCAN_B, 0, stream>>>(deg, rowp, bsum, N);
  scan2_kernel<<<1, 128, 0, stream>>>(bsum, NB);
  scan3_kernel<<<NB, SCAN_B, 0, stream>>>(rowp, bsum, N, E);
  scatter_kernel<<<(E + 255) / 256, 256, 0, stream>>>(dstp, rowp, fill, eids, E);
  if (sorted) {
    permute_kernel<<<(E + 255) / 256, 256, 0, stream>>>(
        eids, srcp, (const float4*)edge_attr, src_s, (float4*)attr_s, E);
  }

  // ---- 4 GINE layers ----
  const int gatherBlocks = (N + 3) / 4;
  const int mlpBlocks    = (N + 255) / 256;
  for (int l = 0; l < 4; ++l) {
    if (sorted) {
      gather_kernel<true><<<gatherBlocks, 256, 0, stream>>>(
          zbuf, scsh, attr_s, src_s, nullptr, rowp, edge_W, edge_b, gbuf, N, l > 0);
    } else {
      gather_kernel<false><<<gatherBlocks, 256, 0, stream>>>(
          zbuf, scsh, edge_attr, srcp, eids, rowp, edge_W, edge_b, gbuf, N, l > 0);
    }
    hipMemsetAsync(stat, 0, 512, stream);
    mlp_fused_kernel<<<mlpBlocks, 256, 0, stream>>>(
        gbuf, zbuf, mlp1_W + (size_t)l * 4096, mlp1_b + (size_t)l * 64,
        mlp2_W + (size_t)l * 4096, mlp2_b + (size_t)l * 64, stat, N);
    bnfinal_kernel<<<1, 64, 0, stream>>>(
        stat, bn_gamma + (size_t)l * 64, bn_beta + (size_t)l * 64, scsh,
        1.0f / (float)N);
  }

  // ---- pooling + head ----
  hipMemsetAsync(sums, 0, (size_t)NGRAPH * 64 * 4, stream);
  hipMemsetAsync(cnts, 0, (size_t)NGRAPH * 4, stream);
  const int poolWaves = (N + 63) / 64;
  pool_kernel<<<(poolWaves + 3) / 4, 256, 0, stream>>>(zbuf, scsh, batch, sums, cnts, N);
  head_kernel<<<NGRAPH, 256, 0, stream>>>(
      sums, cnts, head1_W, head1_b, head2_W, head2_b, head3_W, head3_b, out);
}

// Round 3
// 1220.267 us; speedup vs baseline: 1.7281x; 1.3017x over previous
//
#include <hip/hip_runtime.h>

#define SCAN_B 1024
#define NGRAPH 128
typedef unsigned short u16;
typedef unsigned int u32;

__device__ __forceinline__ float bf2f(u16 u) {
  return __uint_as_float(((u32)u) << 16);
}
__device__ __forceinline__ u16 f2bf(float f) {
  u32 u = __float_as_uint(f);
  return (u16)((u + 0x7fffu + ((u >> 16) & 1u)) >> 16);
}

// ---------------- node encoder: h = x @ W(32x64) + b  -> bf16 --------------
__global__ __launch_bounds__(256) void node_enc_kernel(
    const float* __restrict__ x, const float* __restrict__ W,
    const float* __restrict__ b, u16* __restrict__ zb, int N)
{
  int lane = threadIdx.x & 63;
  int wave = (blockIdx.x * blockDim.x + threadIdx.x) >> 6;
  int nw = (gridDim.x * blockDim.x) >> 6;
  float wcol[32];
#pragma unroll
  for (int k = 0; k < 32; ++k) wcol[k] = W[k * 64 + lane];
  float bb = b[lane];
  for (int n = wave; n < N; n += nw) {
    const float4* xr = (const float4*)(x + (size_t)n * 32);
    float acc = bb;
#pragma unroll
    for (int c = 0; c < 8; ++c) {
      float4 v = xr[c];
      acc = fmaf(v.x, wcol[4 * c + 0], acc);
      acc = fmaf(v.y, wcol[4 * c + 1], acc);
      acc = fmaf(v.z, wcol[4 * c + 2], acc);
      acc = fmaf(v.w, wcol[4 * c + 3], acc);
    }
    zb[(size_t)n * 64 + lane] = f2bf(acc);
  }
}

// ---------------- CSR build ------------------------------------------------
__global__ __launch_bounds__(256) void count_kernel(
    const int* __restrict__ dst, int* __restrict__ deg, int E)
{
  int e = blockIdx.x * blockDim.x + threadIdx.x;
  if (e < E) atomicAdd(&deg[dst[e]], 1);
}

__global__ __launch_bounds__(SCAN_B) void scan1_kernel(
    const int* __restrict__ deg, int* __restrict__ rowp,
    int* __restrict__ bsum, int N)
{
  __shared__ int s[SCAN_B];
  int tid = threadIdx.x;
  int i = blockIdx.x * SCAN_B + tid;
  int v = (i < N) ? deg[i] : 0;
  s[tid] = v;
  __syncthreads();
  for (int off = 1; off < SCAN_B; off <<= 1) {
    int t = (tid >= off) ? s[tid - off] : 0;
    __syncthreads();
    s[tid] += t;
    __syncthreads();
  }
  if (i < N) rowp[i] = s[tid] - v;          // exclusive
  if (tid == SCAN_B - 1) bsum[blockIdx.x] = s[tid];
}

__global__ __launch_bounds__(128) void scan2_kernel(int* __restrict__ bsum, int NB)
{
  __shared__ int s[128];
  int tid = threadIdx.x;
  int v = (tid < NB) ? bsum[tid] : 0;
  s[tid] = v;
  __syncthreads();
  for (int off = 1; off < 128; off <<= 1) {
    int t = (tid >= off) ? s[tid - off] : 0;
    __syncthreads();
    s[tid] += t;
    __syncthreads();
  }
  if (tid < NB) bsum[tid] = s[tid] - v;     // exclusive block offsets
}

__global__ __launch_bounds__(SCAN_B) void scan3_kernel(
    int* __restrict__ rowp, const int* __restrict__ bsum, int N, int E)
{
  int i = blockIdx.x * SCAN_B + threadIdx.x;
  if (i < N) rowp[i] += bsum[blockIdx.x];
  if (i == 0) rowp[N] = E;
}

__global__ __launch_bounds__(256) void scatter_kernel(
    const int* __restrict__ dst, const int* __restrict__ rowp,
    int* __restrict__ fill, int* __restrict__ eids, int E)
{
  int e = blockIdx.x * blockDim.x + threadIdx.x;
  if (e < E) {
    int d = dst[e];
    int pos = rowp[d] + atomicAdd(&fill[d], 1);
    eids[pos] = e;
  }
}

// ------- precompute CSR-ordered edge encodings e = attr @ eW + eb (bf16) ---
__global__ __launch_bounds__(256) void compute_e_kernel(
    const int* __restrict__ eids, const int* __restrict__ src,
    const float* __restrict__ attr, const float* __restrict__ eW,
    const float* __restrict__ eb_, int* __restrict__ src_s,
    u16* __restrict__ e_s, int E)
{
  int lane = threadIdx.x & 63;
  int wave = (blockIdx.x * blockDim.x + threadIdx.x) >> 6;
  int nw = (gridDim.x * blockDim.x) >> 6;
  float wcol[16];
#pragma unroll
  for (int k = 0; k < 16; ++k) wcol[k] = eW[k * 64 + lane];
  const float eb = eb_[lane];

  auto edot = [&](int eid) -> float {
    const float4* ar = (const float4*)(attr + (size_t)eid * 16);
    float4 a0 = ar[0], a1 = ar[1], a2 = ar[2], a3 = ar[3];
    float m = eb;
    m = fmaf(a0.x, wcol[0], m);  m = fmaf(a0.y, wcol[1], m);
    m = fmaf(a0.z, wcol[2], m);  m = fmaf(a0.w, wcol[3], m);
    m = fmaf(a1.x, wcol[4], m);  m = fmaf(a1.y, wcol[5], m);
    m = fmaf(a1.z, wcol[6], m);  m = fmaf(a1.w, wcol[7], m);
    m = fmaf(a2.x, wcol[8], m);  m = fmaf(a2.y, wcol[9], m);
    m = fmaf(a2.z, wcol[10], m); m = fmaf(a2.w, wcol[11], m);
    m = fmaf(a3.x, wcol[12], m); m = fmaf(a3.y, wcol[13], m);
    m = fmaf(a3.z, wcol[14], m); m = fmaf(a3.w, wcol[15], m);
    return m;
  };

  for (int b64 = wave << 6; b64 < E; b64 += nw << 6) {
    int nb = E - b64; if (nb > 64) nb = 64;
    int eid = 0;
    if (lane < nb) {
      eid = eids[b64 + lane];
      src_s[b64 + lane] = src[eid];
    }
    int t = 0;
    for (; t + 4 <= nb; t += 4) {
      int e0 = __shfl(eid, t, 64),     e1 = __shfl(eid, t + 1, 64);
      int e2 = __shfl(eid, t + 2, 64), e3 = __shfl(eid, t + 3, 64);
      float m0 = edot(e0), m1 = edot(e1), m2 = edot(e2), m3 = edot(e3);
      size_t o = (size_t)(b64 + t) * 64 + lane;
      __builtin_nontemporal_store(f2bf(m0), &e_s[o]);
      __builtin_nontemporal_store(f2bf(m1), &e_s[o + 64]);
      __builtin_nontemporal_store(f2bf(m2), &e_s[o + 128]);
      __builtin_nontemporal_store(f2bf(m3), &e_s[o + 192]);
    }
    for (; t < nb; ++t) {
      int e0 = __shfl(eid, t, 64);
      __builtin_nontemporal_store(f2bf(edot(e0)),
                                  &e_s[(size_t)(b64 + t) * 64 + lane]);
    }
  }
}

// ---------------- gather ---------------------------------------------------
// g[i] = hval(zb[i]) + sum_{e: dst=i} relu(hval(zb[src_e]) + e_e)
// hval(v) = use_bn ? relu(v*sc+sh) : v
template<bool SORTED>
__global__ __launch_bounds__(256) void gather_kernel(
    const u16* __restrict__ zb, const float* __restrict__ scsh,
    const u16* __restrict__ e_s, const int* __restrict__ srcv,
    const int* __restrict__ eids, const int* __restrict__ rowp,
    const float* __restrict__ attr, const float* __restrict__ eW,
    const float* __restrict__ eb_, float* __restrict__ g, int N, int use_bn)
{
  int lane = threadIdx.x & 63;
  int node = (blockIdx.x * blockDim.x + threadIdx.x) >> 6;
  if (node >= N) return;

  float sc = 1.f, sh = 0.f;
  if (use_bn) { sc = scsh[lane]; sh = scsh[64 + lane]; }
  auto hval = [&](float zz) -> float {
    float v = fmaf(zz, sc, sh);
    return use_bn ? fmaxf(v, 0.f) : v;
  };

  float wcol[16];
  float eb = 0.f;
  if (!SORTED) {
#pragma unroll
    for (int k = 0; k < 16; ++k) wcol[k] = eW[k * 64 + lane];
    eb = eb_[lane];
  }
  auto edot = [&](int eid) -> float {
    const float4* ar = (const float4*)(attr + (size_t)eid * 16);
    float4 a0 = ar[0], a1 = ar[1], a2 = ar[2], a3 = ar[3];
    float m = eb;
    m = fmaf(a0.x, wcol[0], m);  m = fmaf(a0.y, wcol[1], m);
    m = fmaf(a0.z, wcol[2], m);  m = fmaf(a0.w, wcol[3], m);
    m = fmaf(a1.x, wcol[4], m);  m = fmaf(a1.y, wcol[5], m);
    m = fmaf(a1.z, wcol[6], m);  m = fmaf(a1.w, wcol[7], m);
    m = fmaf(a2.x, wcol[8], m);  m = fmaf(a2.y, wcol[9], m);
    m = fmaf(a2.z, wcol[10], m); m = fmaf(a2.w, wcol[11], m);
    m = fmaf(a3.x, wcol[12], m); m = fmaf(a3.y, wcol[13], m);
    m = fmaf(a3.z, wcol[14], m); m = fmaf(a3.w, wcol[15], m);
    return m;
  };

  const int j0 = rowp[node], j1 = rowp[node + 1];
  float acc0 = hval(bf2f(zb[(size_t)node * 64 + lane]));
  float acc1 = 0.f;

  for (int base = j0; base < j1; base += 64) {
    int nb = j1 - base; if (nb > 64) nb = 64;
    int iv = 0;
    if (lane < nb) iv = SORTED ? srcv[base + lane] : eids[base + lane];
    int t = 0;
    if (SORTED) {
      for (; t + 8 <= nb; t += 8) {
        int s0 = __shfl(iv, t, 64),     s1 = __shfl(iv, t + 1, 64);
        int s2 = __shfl(iv, t + 2, 64), s3 = __shfl(iv, t + 3, 64);
        int s4 = __shfl(iv, t + 4, 64), s5 = __shfl(iv, t + 5, 64);
        int s6 = __shfl(iv, t + 6, 64), s7 = __shfl(iv, t + 7, 64);
        u16 z0 = zb[(size_t)s0 * 64 + lane], z1 = zb[(size_t)s1 * 64 + lane];
        u16 z2 = zb[(size_t)s2 * 64 + lane], z3 = zb[(size_t)s3 * 64 + lane];
        u16 z4 = zb[(size_t)s4 * 64 + lane], z5 = zb[(size_t)s5 * 64 + lane];
        u16 z6 = zb[(size_t)s6 * 64 + lane], z7 = zb[(size_t)s7 * 64 + lane];
        const u16* ep = &e_s[(size_t)(base + t) * 64 + lane];
        u16 e0 = __builtin_nontemporal_load(ep);
        u16 e1 = __builtin_nontemporal_load(ep + 64);
        u16 e2 = __builtin_nontemporal_load(ep + 128);
        u16 e3 = __builtin_nontemporal_load(ep + 192);
        u16 e4 = __builtin_nontemporal_load(ep + 256);
        u16 e5 = __builtin_nontemporal_load(ep + 320);
        u16 e6 = __builtin_nontemporal_load(ep + 384);
        u16 e7 = __builtin_nontemporal_load(ep + 448);
        float a0 = fmaxf(hval(bf2f(z0)) + bf2f(e0), 0.f);
        float a1 = fmaxf(hval(bf2f(z1)) + bf2f(e1), 0.f);
        float a2 = fmaxf(hval(bf2f(z2)) + bf2f(e2), 0.f);
        float a3 = fmaxf(hval(bf2f(z3)) + bf2f(e3), 0.f);
        float a4 = fmaxf(hval(bf2f(z4)) + bf2f(e4), 0.f);
        float a5 = fmaxf(hval(bf2f(z5)) + bf2f(e5), 0.f);
        float a6 = fmaxf(hval(bf2f(z6)) + bf2f(e6), 0.f);
        float a7 = fmaxf(hval(bf2f(z7)) + bf2f(e7), 0.f);
        acc0 += (a0 + a1) + (a2 + a3);
        acc1 += (a4 + a5) + (a6 + a7);
      }
      for (; t < nb; ++t) {
        int s0 = __shfl(iv, t, 64);
        u16 z0 = zb[(size_t)s0 * 64 + lane];
        u16 e0 = __builtin_nontemporal_load(&e_s[(size_t)(base + t) * 64 + lane]);
        acc0 += fmaxf(hval(bf2f(z0)) + bf2f(e0), 0.f);
      }
    } else {
      for (; t < nb; ++t) {
        int i0 = __shfl(iv, t, 64);
        int s0 = srcv[i0];
        u16 z0 = zb[(size_t)s0 * 64 + lane];
        float m0 = edot(i0);
        acc0 += fmaxf(hval(bf2f(z0)) + m0, 0.f);
      }
    }
  }
  g[(size_t)node * 64 + lane] = acc0 + acc1;
}

// ---------------- fused MLP (two 64x64 matmuls) + BN stats -----------------
__global__ __launch_bounds__(256, 2) void mlp_fused_kernel(
    const float* __restrict__ g, u16* __restrict__ zb,
    const float* __restrict__ W1, const float* __restrict__ b1,
    const float* __restrict__ W2, const float* __restrict__ b2,
    float* __restrict__ stat, int N)
{
  __shared__ float sred[2][4][64];
  int tid = threadIdx.x, lane = tid & 63, w = tid >> 6;
  int row = blockIdx.x * 256 + tid;
  bool active = row < N;
  int r = active ? row : (N - 1);

  float y1[64];
#pragma unroll
  for (int d = 0; d < 64; ++d) y1[d] = b1[d];
  const float4* gr = (const float4*)(g + (size_t)r * 64);
  for (int kk = 0; kk < 16; ++kk) {
    float4 v = gr[kk];
    const float* wp = W1 + kk * 256;
#pragma unroll
    for (int d = 0; d < 64; ++d)
      y1[d] += fmaf(v.x, wp[d], fmaf(v.y, wp[64 + d],
               fmaf(v.z, wp[128 + d], v.w * wp[192 + d])));
  }
#pragma unroll
  for (int d = 0; d < 64; ++d) y1[d] = fmaxf(y1[d], 0.f);

  float y2[64];
#pragma unroll
  for (int d = 0; d < 64; ++d) y2[d] = b2[d];
  for (int kk = 0; kk < 16; ++kk) {
    const float* wp = W2 + kk * 256;
    float vx = y1[4 * kk], vy = y1[4 * kk + 1];
    float vz = y1[4 * kk + 2], vw = y1[4 * kk + 3];
#pragma unroll
    for (int d = 0; d < 64; ++d)
      y2[d] += fmaf(vx, wp[d], fmaf(vy, wp[64 + d],
               fmaf(vz, wp[128 + d], vw * wp[192 + d])));
  }

  if (active) {
    u32 packed[32];
#pragma unroll
    for (int c = 0; c < 32; ++c)
      packed[c] = (u32)f2bf(y2[2 * c]) | ((u32)f2bf(y2[2 * c + 1]) << 16);
    uint4* zr = (uint4*)(zb + (size_t)row * 64);
#pragma unroll
    for (int c = 0; c < 8; ++c)
      zr[c] = make_uint4(packed[4 * c], packed[4 * c + 1],
                         packed[4 * c + 2], packed[4 * c + 3]);
  }

  // per-channel sum / sumsq: butterfly within wave, channel d lands on lane d
  float mask = active ? 1.f : 0.f;
  float rs1 = 0.f, rs2 = 0.f;
#pragma unroll
  for (int d = 0; d < 64; ++d) {
    float a = y2[d] * mask;
    float bq = a * a;
#pragma unroll
    for (int m = 1; m < 64; m <<= 1) {
      a += __shfl_xor(a, m, 64);
      bq += __shfl_xor(bq, m, 64);
    }
    if (lane == d) { rs1 = a; rs2 = bq; }
  }
  sred[0][w][lane] = rs1;
  sred[1][w][lane] = rs2;
  __syncthreads();
  if (tid < 64) {
    atomicAdd(&stat[tid],
              sred[0][0][tid] + sred[0][1][tid] + sred[0][2][tid] + sred[0][3][tid]);
  } else if (tid < 128) {
    int c = tid - 64;
    atomicAdd(&stat[64 + c],
              sred[1][0][c] + sred[1][1][c] + sred[1][2][c] + sred[1][3][c]);
  }
}

// ---------------- BN finalize ----------------------------------------------
__global__ __launch_bounds__(64) void bnfinal_kernel(
    const float* __restrict__ stat, const float* __restrict__ gamma,
    const float* __restrict__ beta, float* __restrict__ scsh, float invN)
{
  int d = threadIdx.x;
  float mu = stat[d] * invN;
  float var = stat[64 + d] * invN - mu * mu;
  var = fmaxf(var, 0.f);
  float sc = gamma[d] * rsqrtf(var + 1e-5f);
  scsh[d] = sc;
  scsh[64 + d] = beta[d] - mu * sc;
}

// ---------------- pooling (fused BN-normalize + relu) ----------------------
__global__ __launch_bounds__(256) void pool_kernel(
    const u16* __restrict__ zb, const float* __restrict__ scsh,
    const int* __restrict__ batch,
    float* __restrict__ sums, float* __restrict__ cnts, int N)
{
  int lane = threadIdx.x & 63;
  int wave = (blockIdx.x * blockDim.x + threadIdx.x) >> 6;
  int r0 = wave * 64;
  if (r0 >= N) return;
  float sc = scsh[lane], sh = scsh[64 + lane];
  int r1 = min(r0 + 64, N);
  int cur = batch[r0];
  float acc = 0.f;
  int cnt = 0;
  for (int r = r0; r < r1; ++r) {
    int bg = batch[r];
    if (bg != cur) {
      atomicAdd(&sums[(size_t)cur * 64 + lane], acc);
      if (lane == 0) atomicAdd(&cnts[cur], (float)cnt);
      acc = 0.f; cnt = 0; cur = bg;
    }
    acc += fmaxf(fmaf(bf2f(zb[(size_t)r * 64 + lane]), sc, sh), 0.f);
    cnt++;
  }
  atomicAdd(&sums[(size_t)cur * 64 + lane], acc);
  if (lane == 0) atomicAdd(&cnts[cur], (float)cnt);
}

// ---------------- head: per-graph MLP --------------------------------------
__global__ __launch_bounds__(256) void head_kernel(
    const float* __restrict__ sums, const float* __restrict__ cnts,
    const float* __restrict__ W1, const float* __restrict__ b1,
    const float* __restrict__ W2, const float* __restrict__ b2,
    const float* __restrict__ W3, const float* __restrict__ b3,
    float* __restrict__ out)
{
  __shared__ float gf[128];
  __shared__ float h1s[256];
  __shared__ float h2s[128];
  int g = blockIdx.x, t = threadIdx.x;
  if (t < 64) {
    float sv = sums[(size_t)g * 64 + t];
    gf[t] = sv;
    gf[64 + t] = sv / fmaxf(cnts[g], 1.f);
  }
  __syncthreads();
  float a = b1[t];
  for (int k = 0; k < 128; ++k) a = fmaf(gf[k], W1[k * 256 + t], a);
  h1s[t] = fmaxf(a, 0.f);
  __syncthreads();
  if (t < 128) {
    float a2 = b2[t];
    for (int k = 0; k < 256; ++k) a2 = fmaf(h1s[k], W2[k * 128 + t], a2);
    h2s[t] = fmaxf(a2, 0.f);
  }
  __syncthreads();
  if (t == 0) {
    float s = b3[0];
    for (int k = 0; k < 128; ++k) s = fmaf(h2s[k], W3[k], s);
    out[g] = s;
  }
}

// ---------------------------------------------------------------------------
extern "C" void kernel_launch(void* const* d_in, const int* in_sizes, int n_in,
                              void* d_out, int out_size, void* d_ws, size_t ws_size,
                              hipStream_t stream)
{
  const float* x         = (const float*)d_in[0];
  const float* edge_attr = (const float*)d_in[1];
  const int*   ei        = (const int*)  d_in[2];
  const int*   batch     = (const int*)  d_in[3];
  const float* node_W    = (const float*)d_in[4];
  const float* node_b    = (const float*)d_in[5];
  const float* edge_W    = (const float*)d_in[6];
  const float* edge_b    = (const float*)d_in[7];
  const float* mlp1_W    = (const float*)d_in[8];
  const float* mlp1_b    = (const float*)d_in[9];
  const float* mlp2_W    = (const float*)d_in[10];
  const float* mlp2_b    = (const float*)d_in[11];
  const float* bn_gamma  = (const float*)d_in[12];
  const float* bn_beta   = (const float*)d_in[13];
  const float* head1_W   = (const float*)d_in[14];
  const float* head1_b   = (const float*)d_in[15];
  const float* head2_W   = (const float*)d_in[16];
  const float* head2_b   = (const float*)d_in[17];
  const float* head3_W   = (const float*)d_in[18];
  const float* head3_b   = (const float*)d_in[19];
  float* out = (float*)d_out;
  (void)n_in; (void)out_size;

  const int N = in_sizes[0] / 32;       // 100000
  const int E = in_sizes[2] / 2;        // 1600000
  const int* srcp = ei;
  const int* dstp = ei + E;

  auto al = [](size_t b) { return (b + 255) & ~(size_t)255; };
  const size_t sz_zb   = al((size_t)N * 64 * 2);   // bf16 activations
  const size_t sz_g    = al((size_t)N * 64 * 4);   // f32 gather output
  const size_t sz_es   = al((size_t)E * 64 * 2);   // bf16 edge encodings
  const size_t sz_src  = al((size_t)E * 4);
  const size_t sz_rowp = al((size_t)(N + 1) * 4);
  const size_t sz_eids = al((size_t)E * 4);
  const size_t sz_small = al(512) * 3 + al(NGRAPH * 64 * 4) + al(NGRAPH * 4);

  const size_t need_sorted = sz_zb + sz_g + sz_es + sz_src + sz_rowp + sz_small;
  const bool sorted = ws_size >= need_sorted;

  char* p = (char*)d_ws;
  auto take = [&](size_t b) -> char* { char* q = p; p += b; return q; };

  u16*   zb   = (u16*)  take(sz_zb);
  float* gbuf = (float*)take(sz_g);
  int*   rowp = (int*)  take(sz_rowp);
  float* stat = (float*)take(al(512));
  float* scsh = (float*)take(al(512));
  int*   bsum = (int*)  take(al(512));
  float* sums = (float*)take(al(NGRAPH * 64 * 4));
  float* cnts = (float*)take(al(NGRAPH * 4));

  u16* e_s   = nullptr;
  int* src_s = nullptr;
  int* eids;
  int* deg;
  int* fill;
  if (sorted) {
    e_s   = (u16*)take(sz_es);
    src_s = (int*)take(sz_src);
    // scratch (dead after compute_e) aliases gbuf
    deg  = (int*)gbuf;
    fill = (int*)((char*)gbuf + al((size_t)N * 4));
    eids = (int*)((char*)gbuf + 2 * al((size_t)N * 4));
  } else {
    eids = (int*)take(sz_eids);
    deg  = (int*)gbuf;
    fill = (int*)((char*)gbuf + al((size_t)N * 4));
  }

  const int NB = (N + SCAN_B - 1) / SCAN_B;

  // ---- encoders + CSR build ----
  hipMemsetAsync(deg,  0, (size_t)N * 4, stream);
  hipMemsetAsync(fill, 0, (size_t)N * 4, stream);

  node_enc_kernel<<<2048, 256, 0, stream>>>(x, node_W, node_b, zb, N);
  count_kernel<<<(E + 255) / 256, 256, 0, stream>>>(dstp, deg, E);
  scan1_kernel<<<NB, SCAN_B, 0, stream>>>(deg, rowp, bsum, N);
  scan2_kernel<<<1, 128, 0, stream>>>(bsum, NB);
  scan3_kernel<<<NB, SCAN_B, 0, stream>>>(rowp, bsum, N, E);
  scatter_kernel<<<(E + 255) / 256, 256, 0, stream>>>(dstp, rowp, fill, eids, E);
  if (sorted) {
    compute_e_kernel<<<6250, 256, 0, stream>>>(
        eids, srcp, edge_attr, edge_W, edge_b, src_s, e_s, E);
  }

  // ---- 4 GINE layers ----
  const int gatherBlocks = (N + 3) / 4;
  const int mlpBlocks    = (N + 255) / 256;
  for (int l = 0; l < 4; ++l) {
    if (sorted) {
      gather_kernel<true><<<gatherBlocks, 256, 0, stream>>>(
          zb, scsh, e_s, src_s, nullptr, rowp, nullptr, nullptr, nullptr,
          gbuf, N, l > 0);
    } else {
      gather_kernel<false><<<gatherBlocks, 256, 0, stream>>>(
          zb, scsh, nullptr, srcp, eids, rowp, edge_attr, edge_W, edge_b,
          gbuf, N, l > 0);
    }
    hipMemsetAsync(stat, 0, 512, stream);
    mlp_fused_kernel<<<mlpBlocks, 256, 0, stream>>>(
        gbuf, zb, mlp1_W + (size_t)l * 4096, mlp1_b + (size_t)l * 64,
        mlp2_W + (size_t)l * 4096, mlp2_b + (size_t)l * 64, stat, N);
    bnfinal_kernel<<<1, 64, 0, stream>>>(
        stat, bn_gamma + (size_t)l * 64, bn_beta + (size_t)l * 64, scsh,
        1.0f / (float)N);
  }

  // ---- pooling + head ----
  hipMemsetAsync(sums, 0, (size_t)NGRAPH * 64 * 4, stream);
  hipMemsetAsync(cnts, 0, (size_t)NGRAPH * 4, stream);
  const int poolWaves = (N + 63) / 64;
  pool_kernel<<<(poolWaves + 3) / 4, 256, 0, stream>>>(zb, scsh, batch, sums, cnts, N);
  head_kernel<<<NGRAPH, 256, 0, stream>>>(
      sums, cnts, head1_W, head1_b, head2_W, head2_b, head3_W, head3_b, out);
}